// Round 12
// baseline (28.385 us; speedup 1.0000x reference)
//
#include <hip/hip_runtime.h>

#define LDIM 512
#define SITES (LDIM * LDIM)
#define H 32                    // rows per strip (per wave)
#define STRIPS (LDIM / H)       // 16 strips per batch

__device__ __forceinline__ float spin_of(float x0, float x1) {
    // argmax tie-break: index 0 wins on equality -> spin -1
    return x1 > x0 ? 1.0f : -1.0f;
}

// One single-wave block per strip: 64 lanes x 8 cols = full 512-wide row.
// Walks H=32 rows with a 3-row rolling spin window and a distance-3 load
// pipeline (2 row-loads in flight per wave -> 32 KB/CU at 4 waves/CU);
// every row loaded once (+2 halo rows -> 1.0625x amplification).
__global__ __launch_bounds__(64) void ising_strip(
        const float* __restrict__ x, float4* __restrict__ part) {
    const int b     = blockIdx.y;
    const int strip = blockIdx.x;
    const int lane  = threadIdx.x;
    const int r0    = strip * H;

    const float* xb = x + (size_t)b * (size_t)(SITES * 2);

    float4 xv[4][4];   // 4-deep ring: rows i (consuming), i+1, i+2 (in flight)
    float  sp[3][8];   // rolling spins: rows i-1, i, i+1
    float A = 0.f, Hs = 0.f, T12 = 0.f;

    #define LOADROW(row, dst)                                                  \
        do {                                                                   \
            const float4* p_ =                                                 \
                (const float4*)(xb + (size_t)(row) * (LDIM * 2));              \
            _Pragma("unroll")                                                  \
            for (int q_ = 0; q_ < 4; ++q_) (dst)[q_] = p_[lane * 4 + q_];      \
        } while (0)
    #define SPINS(v, s)                                                        \
        do {                                                                   \
            _Pragma("unroll")                                                  \
            for (int q_ = 0; q_ < 4; ++q_) {                                   \
                (s)[2 * q_]     = spin_of((v)[q_].x, (v)[q_].y);               \
                (s)[2 * q_ + 1] = spin_of((v)[q_].z, (v)[q_].w);               \
            }                                                                  \
        } while (0)

    // prologue: issue halo(r0-1), rows r0, r0+1, r0+2 loads (2 ahead in ring)
    {
        float4 tmp[4];
        LOADROW((r0 + LDIM - 1) & (LDIM - 1), tmp);
        LOADROW(r0, xv[0]);
        LOADROW(r0 + 1, xv[1]);            // interior: H >= 3
        LOADROW(r0 + 2, xv[2]);
        SPINS(tmp, sp[0]);
        SPINS(xv[0], sp[1]);
    }

    const int laneL = (lane + 63) & 63;
    const int laneR = (lane + 1) & 63;

    #pragma unroll
    for (int i = 0; i < H; ++i) {
        // issue load of row r0+i+3 (lands two iterations from now);
        // interior rows need no wrap; r0+H wraps for the last strip
        if (i < H - 3)       LOADROW(r0 + i + 3, xv[(i + 3) & 3]);
        else if (i == H - 3) LOADROW((r0 + H) & (LDIM - 1), xv[(i + 3) & 3]);

        float* sP = sp[i % 3];          // row r0+i-1
        float* sC = sp[(i + 1) % 3];    // row r0+i
        float* sN = sp[(i + 2) % 3];    // row r0+i+1
        SPINS(xv[(i + 1) & 3], sN);     // consumes load issued at iter i-2

        const float sl = __shfl(sC[7], laneL);  // torus col wrap (wave = row)
        const float sr = __shfl(sC[0], laneR);

        #pragma unroll
        for (int k = 0; k < 8; ++k) {
            const float lft = (k == 0) ? sl : sC[k - 1];
            const float rgt = (k == 7) ? sr : sC[k + 1];
            const float h   = (lft + rgt) + (sP[k] + sN[k]);
            const float4 v  = xv[i & 3][k >> 1];
            const float x0  = (k & 1) ? v.z : v.x;
            const float x1  = (k & 1) ? v.w : v.y;
            A   += x0 + x1;
            Hs   = fmaf(sC[k], h, Hs);
            const float g = (sC[k] > 0.f) ? x0 : -x1;  // s(x0+x1)+(x0-x1) = 2g
            T12  = fmaf(g, h, T12);
        }
    }

    #pragma unroll
    for (int off = 32; off; off >>= 1) {
        A   += __shfl_down(A,   off);
        Hs  += __shfl_down(Hs,  off);
        T12 += __shfl_down(T12, off);
    }
    if (lane == 0) part[b * STRIPS + strip] = make_float4(A, Hs, T12, 0.f);

    #undef LOADROW
    #undef SPINS
}

// One block (single wave) per batch: reduce STRIPS partials, apply closed form.
__global__ __launch_bounds__(64) void ising_final(
        const float4* __restrict__ part, float* __restrict__ out) {
    const int b = blockIdx.x;
    const int t = threadIdx.x;
    float A = 0.f, Hs = 0.f, T12 = 0.f;
    if (t < STRIPS) {
        float4 v = part[b * STRIPS + t];
        A = v.x; Hs = v.y; T12 = v.z;
    }
    #pragma unroll
    for (int off = 8; off; off >>= 1) {
        A   += __shfl_down(A,   off);
        Hs  += __shfl_down(Hs,  off);
        T12 += __shfl_down(T12, off);
    }
    if (t == 0) {
        out[b] = (-0.5f * Hs * A + 2.f * T12) * (1.0f / (float)SITES);
    }
}

extern "C" void kernel_launch(void* const* d_in, const int* in_sizes, int n_in,
                              void* d_out, int out_size, void* d_ws, size_t ws_size,
                              hipStream_t stream) {
    const float* x = (const float*)d_in[0];
    float* out = (float*)d_out;
    float4* part = (float4*)d_ws;   // B * STRIPS float4 partials (16 KiB for B=64)

    const int B = in_sizes[0] / (SITES * 2);

    dim3 grid(STRIPS, B);           // 16 x 64 = 1024 single-wave blocks
    ising_strip<<<grid, 64, 0, stream>>>(x, part);
    ising_final<<<B, 64, 0, stream>>>(part, out);
}